// Round 16
// baseline (207.443 us; speedup 1.0000x reference)
//
#include <hip/hip_runtime.h>
#include <hip/hip_fp16.h>

typedef _Float16 f16;
typedef _Float16 f16x8 __attribute__((ext_vector_type(8)));
typedef float f32x4 __attribute__((ext_vector_type(4)));

__device__ __forceinline__ f16x8 relu8(f16x8 a) {
#if __has_builtin(__builtin_elementwise_max)
  return __builtin_elementwise_max(a, (f16x8)(f16)0);   // v_pk_max_f16 x4
#else
  f16x8 r;
#pragma unroll
  for (int i = 0; i < 8; i++) r[i] = a[i] > (f16)0 ? a[i] : (f16)0;
  return r;
#endif
}

__device__ __forceinline__ f16x8 bcast8(f16 s) {
  return (f16x8){s, s, s, s, s, s, s, s};
}

// ---------------------------------------------------------------------------
// prep: Wtp[frag=cg*32+kb2][lane*8+e] = f16(W2[kb2*32+q*8+e][cg*16+cL])
// (16x16x32 B-fragment order; nh slice = Wtp[nh*65536..] is 128 KB contiguous)
// Also zeroes the mega-kernel's barrier counter (same stream -> ordered).
// ---------------------------------------------------------------------------
__global__ __launch_bounds__(256) void k_prep(const float* __restrict__ W2,
                                              f16* __restrict__ Wtp,
                                              unsigned int* __restrict__ cnt) {
  if (blockIdx.x == 0 && threadIdx.x == 0) *cnt = 0u;
  const int t = blockIdx.x * 256 + threadIdx.x;
  const int frag = t >> 6, l = t & 63;
  const int cg = frag >> 5, kb2 = frag & 31;
  const int q = l >> 4, cL = l & 15;
  const int n = cg * 16 + cL, k0 = kb2 * 32 + q * 8;
  f16x8 o;
#pragma unroll
  for (int e = 0; e < 8; e++) o[e] = (f16)W2[(k0 + e) * 128 + n];
  *(f16x8*)(Wtp + frag * 512 + l * 8) = o;
}

// ---------------------------------------------------------------------------
// mega: R14's fused kernel (best: 45.8 us, 16x16x32, rg8 x cg4, no prefetch,
// balanced task map) + in-kernel atta. 256 persistent blocks (1/CU, grid ==
// CU count -> co-resident), 512 thr = 8 waves.
// Phase 1: K = triu MLP rows via 320 balanced tasks (R14 map).
// Barrier: threadfence + device-scope atomicAdd; tid0 acquire-spins to 256.
// Phase 2: C = K^T K, 136 triangular 32x32 pairs, one per block (p<136),
// LDS aliased onto w2f. R12/R15 lessons: no software prefetch (240/256 regs),
// 16x16x32 only. WRITE_SIZE ~3 MB expected; >>10 MB = spill canary.
// ---------------------------------------------------------------------------
__global__ __launch_bounds__(512, 2) void k_mega(
    const float* __restrict__ x, const float* __restrict__ W1,
    const float* __restrict__ b1, const float* __restrict__ b2,
    const float* __restrict__ W3, const float* __restrict__ b3,
    const f16* __restrict__ Wtp,
    float* __restrict__ Kp0, float* __restrict__ Kp1,
    unsigned int* __restrict__ cnt, float* __restrict__ C) {
  __shared__ f16 w2f[65536];                 // 128 KB: current nh's B-fragments
  __shared__ f16 w1af[1024], b1f[1024], w1bf[1024];
  __shared__ f16 hat[8192];                  // 16 KB: ha rows for task's 8 i
  __shared__ f16 xs[512];                    // f16(x)

  const int tid = threadIdx.x;
  const int lane = tid & 63, wv = tid >> 6;
  const int cL = lane & 15, q = lane >> 4;

  // --- one-time staging: W1 tables + f16(x)
  if (tid < 128) {
    const int c8 = tid << 3;
    const float4 a0 = *(const float4*)(W1 + c8);
    const float4 a1 = *(const float4*)(W1 + c8 + 4);
    const float4 g0 = *(const float4*)(b1 + c8);
    const float4 g1 = *(const float4*)(b1 + c8 + 4);
    f16x8 oa, og;
    oa[0] = (f16)a0.x; oa[1] = (f16)a0.y; oa[2] = (f16)a0.z; oa[3] = (f16)a0.w;
    oa[4] = (f16)a1.x; oa[5] = (f16)a1.y; oa[6] = (f16)a1.z; oa[7] = (f16)a1.w;
    og[0] = (f16)g0.x; og[1] = (f16)g0.y; og[2] = (f16)g0.z; og[3] = (f16)g0.w;
    og[4] = (f16)g1.x; og[5] = (f16)g1.y; og[6] = (f16)g1.z; og[7] = (f16)g1.w;
    *(f16x8*)(&w1af[c8]) = oa;
    *(f16x8*)(&b1f[c8]) = og;
  } else if (tid < 256) {
    const int c8 = (tid - 128) << 3;
    const float4 a0 = *(const float4*)(W1 + 1024 + c8);
    const float4 a1 = *(const float4*)(W1 + 1024 + c8 + 4);
    f16x8 ob;
    ob[0] = (f16)a0.x; ob[1] = (f16)a0.y; ob[2] = (f16)a0.z; ob[3] = (f16)a0.w;
    ob[4] = (f16)a1.x; ob[5] = (f16)a1.y; ob[6] = (f16)a1.z; ob[7] = (f16)a1.w;
    *(f16x8*)(&w1bf[c8]) = ob;
  } else if (tid < 320) {
    const int c8 = (tid - 256) << 3;
    const float4 x0 = *(const float4*)(x + c8);
    const float4 x1 = *(const float4*)(x + c8 + 4);
    f16x8 ox;
    ox[0] = (f16)x0.x; ox[1] = (f16)x0.y; ox[2] = (f16)x0.z; ox[3] = (f16)x0.w;
    ox[4] = (f16)x1.x; ox[5] = (f16)x1.y; ox[6] = (f16)x1.z; ox[7] = (f16)x1.w;
    *(f16x8*)(&xs[c8]) = ox;
  }

  int cur_nh = -1;

  for (int t = (int)blockIdx.x; t < 320; t += 256) {
    // --- task map (R14): cheap diagonal in {0..63, 256..319}, full in {64..255}
    int nh, jt, s;
    if (t < 64 || t >= 256) {
      const int b = (t < 64) ? t : (t - 256);
      nh = b & 1;
      const int jd = b >> 1;              // 0..31
      const int jt1 = jd >> 4, l = jd & 15;
      if (t < 64) { jt = jt1;            s = jt * 16 + l; }
      else        { jt = (jt1 + 2) & 3;  s = jt * 16 + (15 - l); }
    } else {
      const int f = t - 64;               // 0..191
      nh = f & 1;
      const int jf = f >> 1;              // 0..95
      if (jf < 16)      { jt = 1; s = jf; }
      else if (jf < 48) { jt = 2; s = jf - 16; }
      else              { jt = 3; s = jf - 48; }
    }
    const int i0 = s << 3, j0 = jt << 7;
    float* __restrict__ Kp = nh ? Kp1 : Kp0;

    __syncthreads();                  // prior task's LDS reads done; covers one-time staging
    if (nh != cur_nh) {               // stage this nh's W2 fragments (128 KB)
      const f16* src = Wtp + nh * 65536;
      #pragma unroll
      for (int p = 0; p < 16; p++) {
        const int off = p * 4096 + tid * 8;
        *(f16x8*)(&w2f[off]) = *(const f16x8*)(src + off);
      }
      cur_nh = nh;
    }
    {  // hat[il][k] = f16(x[i0+il]*W1a[k] + b1[k]); 512 thr x 16 f16
      const int il_s = tid >> 6, kb = (tid & 63) << 4;
      const f16x8 xv = bcast8(xs[i0 + il_s]);
      const f16x8 wa0 = *(const f16x8*)(&w1af[kb]);
      const f16x8 wa1 = *(const f16x8*)(&w1af[kb + 8]);
      const f16x8 bb0 = *(const f16x8*)(&b1f[kb]);
      const f16x8 bb1 = *(const f16x8*)(&b1f[kb + 8]);
      *(f16x8*)(&hat[il_s * 1024 + kb])     = xv * wa0 + bb0;
      *(f16x8*)(&hat[il_s * 1024 + kb + 8]) = xv * wa1 + bb1;
    }
    __syncthreads();

    const int i = i0 + wv;
    const int dij = i - j0;
    const int rgmin = (dij > 0) ? (dij >> 4) : 0;   // wave-uniform skip

    f16 xjs[8];
    #pragma unroll
    for (int rg = 0; rg < 8; rg++) xjs[rg] = xs[j0 + rg * 16 + cL];

    f32x4 acc[8][4];
    #pragma unroll
    for (int rg = 0; rg < 8; rg++)
      #pragma unroll
      for (int cg = 0; cg < 4; cg++) acc[rg][cg] = (f32x4){0.f, 0.f, 0.f, 0.f};

    const f16* hrow  = hat + wv * 1024 + q * 8;
    const f16* wrow  = w1bf + q * 8;
    const f16* bbase = w2f + lane * 8;

    for (int kk = 0; kk < 32; ++kk) {
      const f16x8 hv = *(const f16x8*)(hrow + kk * 32);
      const f16x8 wb = *(const f16x8*)(wrow + kk * 32);
      f16x8 bf[4];
      #pragma unroll
      for (int cg = 0; cg < 4; cg++)
        bf[cg] = *(const f16x8*)(bbase + (cg * 32 + kk) * 512);
      #pragma unroll
      for (int rg = 0; rg < 8; rg++) {
        if (rg >= rgmin) {
          const f16x8 af = relu8(bcast8(xjs[rg]) * wb + hv);
          #pragma unroll
          for (int cg = 0; cg < 4; cg++)
            acc[rg][cg] = __builtin_amdgcn_mfma_f32_16x16x32_f16(af, bf[cg], acc[rg][cg], 0, 0, 0);
        }
      }
    }

    // --- epilogue: dot over this nh's 64 n; direct global writes (1 i/wave)
    float b2v[4], w3v[4];
    #pragma unroll
    for (int cg = 0; cg < 4; cg++) {
      b2v[cg] = b2[nh * 64 + cg * 16 + cL];
      w3v[cg] = W3[nh * 64 + cg * 16 + cL];
    }
    const float badd = (nh == 0) ? b3[0] : 0.f;   // b3 added exactly once
    #pragma unroll
    for (int rg = 0; rg < 8; rg++) {
      if (rg >= rgmin) {
        #pragma unroll
        for (int r = 0; r < 4; r++) {
          float ssum = 0.f;
          #pragma unroll
          for (int cg = 0; cg < 4; cg++)
            ssum = fmaf(fmaxf(acc[rg][cg][r] + b2v[cg], 0.f), w3v[cg], ssum);
          ssum += __shfl_xor(ssum, 1, 64);
          ssum += __shfl_xor(ssum, 2, 64);
          ssum += __shfl_xor(ssum, 4, 64);
          ssum += __shfl_xor(ssum, 8, 64);
          if (cL == 0) {
            const int j = j0 + rg * 16 + q * 4 + r;  // C row = q*4 + reg
            if (j >= i) Kp[i * 512 + j] = ssum + badd;
          }
        }
      }
    }
  }

  // ===== device-scope barrier: all 256 blocks' K writes visible ============
  __threadfence();
  __syncthreads();
  if (tid == 0) {
    __hip_atomic_fetch_add(cnt, 1u, __ATOMIC_ACQ_REL, __HIP_MEMORY_SCOPE_AGENT);
    while (__hip_atomic_load(cnt, __ATOMIC_ACQUIRE, __HIP_MEMORY_SCOPE_AGENT) < 256u)
      __builtin_amdgcn_s_sleep(8);
  }
  __syncthreads();

  // ===== phase 2: C = K^T K (K = Kp0+Kp1, triangular), pair per block ======
  const int p = (int)blockIdx.x;
  if (p < 136) {
    int a = 0, rem = p;
    while (rem >= 16 - a) { rem -= 16 - a; a++; }
    const int pb = a * 32, qb = (a + rem) * 32;
    float* sp = (float*)w2f;              // alias: [32][33]
    float* sq = sp + 32 * 33;
    const int tx = tid & 15, ty = (tid >> 4) & 15;   // tid<256 active
    float c00 = 0.f, c01 = 0.f, c10 = 0.f, c11 = 0.f;
    for (int i0 = 0; i0 < pb + 32; i0 += 32) {
      if (tid < 256) {
        #pragma unroll
        for (int r = 0; r < 4; r++) {
          const int e = tid + 256 * r, ii = e >> 5, pp = e & 31;
          const int irow = i0 + ii;
          const int ip = irow * 512 + pb + pp, iq = irow * 512 + qb + pp;
          sp[ii * 33 + pp] = (irow <= pb + pp) ? Kp0[ip] + Kp1[ip] : 0.f;
          sq[ii * 33 + pp] = (irow <= qb + pp) ? Kp0[iq] + Kp1[iq] : 0.f;
        }
      }
      __syncthreads();
      if (tid < 256) {
        #pragma unroll 8
        for (int ii = 0; ii < 32; ii++) {
          const float a0 = sp[ii * 33 + ty * 2], a1 = sp[ii * 33 + ty * 2 + 1];
          const float b0 = sq[ii * 33 + tx * 2], b1 = sq[ii * 33 + tx * 2 + 1];
          c00 = fmaf(a0, b0, c00); c01 = fmaf(a0, b1, c01);
          c10 = fmaf(a1, b0, c10); c11 = fmaf(a1, b1, c11);
        }
      }
      __syncthreads();
    }
    if (tid < 256) {
      const int p0 = pb + ty * 2, q0 = qb + tx * 2;
      C[p0 * 512 + q0] = c00;       C[p0 * 512 + q0 + 1] = c01;
      C[(p0 + 1) * 512 + q0] = c10; C[(p0 + 1) * 512 + q0 + 1] = c11;
      C[q0 * 512 + p0] = c00;       C[(q0 + 1) * 512 + p0] = c01;
      C[q0 * 512 + p0 + 1] = c10;   C[(q0 + 1) * 512 + p0 + 1] = c11;
    }
  }
}

extern "C" void kernel_launch(void* const* d_in, const int* in_sizes, int n_in,
                              void* d_out, int out_size, void* d_ws, size_t ws_size,
                              hipStream_t stream) {
  const float* x  = (const float*)d_in[0];
  const float* W1 = (const float*)d_in[1];
  const float* b1 = (const float*)d_in[2];
  const float* W2 = (const float*)d_in[3];
  const float* b2 = (const float*)d_in[4];
  const float* W3 = (const float*)d_in[5];
  const float* b3 = (const float*)d_in[6];
  float* out = (float*)d_out;
  char* ws = (char*)d_ws;

  f16* Wtp = (f16*)ws;                              // 256 KB packed W2 B-fragments
  float* Kp0 = (float*)(ws + (256 << 10));          // 1 MB partial K (n 0..63)
  float* Kp1 = (float*)(ws + (256 << 10) + (1 << 20));  // 1 MB partial K (n 64..127)
  unsigned int* cnt = (unsigned int*)(ws + (256 << 10) + (2 << 20));

  k_prep<<<64, 256, 0, stream>>>(W2, Wtp, cnt);
  k_mega<<<256, 512, 0, stream>>>(x, W1, b1, b2, W3, b3, Wtp, Kp0, Kp1, cnt, out);
}

// Round 17
// 124.038 us; speedup vs baseline: 1.6724x; 1.6724x over previous
//
#include <hip/hip_runtime.h>
#include <hip/hip_fp16.h>

typedef _Float16 f16;
typedef _Float16 f16x8 __attribute__((ext_vector_type(8)));
typedef float f32x4 __attribute__((ext_vector_type(4)));

__device__ __forceinline__ f16x8 relu8(f16x8 a) {
#if __has_builtin(__builtin_elementwise_max)
  return __builtin_elementwise_max(a, (f16x8)(f16)0);   // v_pk_max_f16 x4
#else
  f16x8 r;
#pragma unroll
  for (int i = 0; i < 8; i++) r[i] = a[i] > (f16)0 ? a[i] : (f16)0;
  return r;
#endif
}

__device__ __forceinline__ f16x8 bcast8(f16 s) {
  return (f16x8){s, s, s, s, s, s, s, s};
}

__device__ __forceinline__ void atomAddF(float* p, float v) {
#if defined(__AMDGCN__)
  unsafeAtomicAdd(p, v);          // native global_atomic_add_f32
#else
  atomicAdd(p, v);
#endif
}

// ---------------------------------------------------------------------------
// prep: Wtp[frag=cg*32+kb2][lane*8+e] = f16(W2[kb2*32+q*8+e][cg*16+cL])
// (16x16x32 B-fragment order; nh slice = Wtp[nh*65536..] is 128 KB contiguous)
// ---------------------------------------------------------------------------
__global__ __launch_bounds__(256) void k_prep(const float* __restrict__ W2,
                                              f16* __restrict__ Wtp) {
  const int t = blockIdx.x * 256 + threadIdx.x;
  const int frag = t >> 6, l = t & 63;
  const int cg = frag >> 5, kb2 = frag & 31;
  const int q = l >> 4, cL = l & 15;
  const int n = cg * 16 + cL, k0 = kb2 * 32 + q * 8;
  f16x8 o;
#pragma unroll
  for (int e = 0; e < 8; e++) o[e] = (f16)W2[(k0 + e) * 128 + n];
  *(f16x8*)(Wtp + frag * 512 + l * 8) = o;
}

// ---------------------------------------------------------------------------
// fused (R14, best known: 45.8 us): 256 persistent blocks, 512 thr = 8 waves.
// Task = 8 i x 128 j x 64 n (one nh) x 1024 k; wave wv owns i = i0+wv,
// rg=8 x cg=4 -> 32 MFMA per 6 ds_read_b128/kk. No software prefetch (R12).
// Balanced task map: 128 cheap diagonal tasks in {0..63,256..319} paired with
// complementary depth; 192 full tasks in {64..255}. 16x16x32 only (R15).
// No in-kernel barrier (R16: device spin barrier cost ~100 us).
// WRITE_SIZE ~1 MB is the no-spill canary.
// ---------------------------------------------------------------------------
__global__ __launch_bounds__(512, 2) void k_fused(
    const float* __restrict__ x, const float* __restrict__ W1,
    const float* __restrict__ b1, const float* __restrict__ b2,
    const float* __restrict__ W3, const float* __restrict__ b3,
    const f16* __restrict__ Wtp,
    float* __restrict__ Kp0, float* __restrict__ Kp1) {
  __shared__ f16 w2f[65536];                 // 128 KB: current nh's B-fragments
  __shared__ f16 w1af[1024], b1f[1024], w1bf[1024];
  __shared__ f16 hat[8192];                  // 16 KB: ha rows for task's 8 i
  __shared__ f16 xs[512];                    // f16(x)

  const int tid = threadIdx.x;
  const int lane = tid & 63, wv = tid >> 6;
  const int cL = lane & 15, q = lane >> 4;

  // --- one-time staging: W1 tables + f16(x)
  if (tid < 128) {
    const int c8 = tid << 3;
    const float4 a0 = *(const float4*)(W1 + c8);
    const float4 a1 = *(const float4*)(W1 + c8 + 4);
    const float4 g0 = *(const float4*)(b1 + c8);
    const float4 g1 = *(const float4*)(b1 + c8 + 4);
    f16x8 oa, og;
    oa[0] = (f16)a0.x; oa[1] = (f16)a0.y; oa[2] = (f16)a0.z; oa[3] = (f16)a0.w;
    oa[4] = (f16)a1.x; oa[5] = (f16)a1.y; oa[6] = (f16)a1.z; oa[7] = (f16)a1.w;
    og[0] = (f16)g0.x; og[1] = (f16)g0.y; og[2] = (f16)g0.z; og[3] = (f16)g0.w;
    og[4] = (f16)g1.x; og[5] = (f16)g1.y; og[6] = (f16)g1.z; og[7] = (f16)g1.w;
    *(f16x8*)(&w1af[c8]) = oa;
    *(f16x8*)(&b1f[c8]) = og;
  } else if (tid < 256) {
    const int c8 = (tid - 128) << 3;
    const float4 a0 = *(const float4*)(W1 + 1024 + c8);
    const float4 a1 = *(const float4*)(W1 + 1024 + c8 + 4);
    f16x8 ob;
    ob[0] = (f16)a0.x; ob[1] = (f16)a0.y; ob[2] = (f16)a0.z; ob[3] = (f16)a0.w;
    ob[4] = (f16)a1.x; ob[5] = (f16)a1.y; ob[6] = (f16)a1.z; ob[7] = (f16)a1.w;
    *(f16x8*)(&w1bf[c8]) = ob;
  } else if (tid < 320) {
    const int c8 = (tid - 256) << 3;
    const float4 x0 = *(const float4*)(x + c8);
    const float4 x1 = *(const float4*)(x + c8 + 4);
    f16x8 ox;
    ox[0] = (f16)x0.x; ox[1] = (f16)x0.y; ox[2] = (f16)x0.z; ox[3] = (f16)x0.w;
    ox[4] = (f16)x1.x; ox[5] = (f16)x1.y; ox[6] = (f16)x1.z; ox[7] = (f16)x1.w;
    *(f16x8*)(&xs[c8]) = ox;
  }

  int cur_nh = -1;

  for (int t = (int)blockIdx.x; t < 320; t += 256) {
    // --- task map (R14): cheap diagonal in {0..63, 256..319}, full in {64..255}
    int nh, jt, s;
    if (t < 64 || t >= 256) {
      const int b = (t < 64) ? t : (t - 256);
      nh = b & 1;
      const int jd = b >> 1;              // 0..31
      const int jt1 = jd >> 4, l = jd & 15;
      if (t < 64) { jt = jt1;            s = jt * 16 + l; }
      else        { jt = (jt1 + 2) & 3;  s = jt * 16 + (15 - l); }
    } else {
      const int f = t - 64;               // 0..191
      nh = f & 1;
      const int jf = f >> 1;              // 0..95
      if (jf < 16)      { jt = 1; s = jf; }
      else if (jf < 48) { jt = 2; s = jf - 16; }
      else              { jt = 3; s = jf - 48; }
    }
    const int i0 = s << 3, j0 = jt << 7;
    float* __restrict__ Kp = nh ? Kp1 : Kp0;

    __syncthreads();                  // prior task's LDS reads done; covers one-time staging
    if (nh != cur_nh) {               // stage this nh's W2 fragments (128 KB)
      const f16* src = Wtp + nh * 65536;
      #pragma unroll
      for (int p = 0; p < 16; p++) {
        const int off = p * 4096 + tid * 8;
        *(f16x8*)(&w2f[off]) = *(const f16x8*)(src + off);
      }
      cur_nh = nh;
    }
    {  // hat[il][k] = f16(x[i0+il]*W1a[k] + b1[k]); 512 thr x 16 f16
      const int il_s = tid >> 6, kb = (tid & 63) << 4;
      const f16x8 xv = bcast8(xs[i0 + il_s]);
      const f16x8 wa0 = *(const f16x8*)(&w1af[kb]);
      const f16x8 wa1 = *(const f16x8*)(&w1af[kb + 8]);
      const f16x8 bb0 = *(const f16x8*)(&b1f[kb]);
      const f16x8 bb1 = *(const f16x8*)(&b1f[kb + 8]);
      *(f16x8*)(&hat[il_s * 1024 + kb])     = xv * wa0 + bb0;
      *(f16x8*)(&hat[il_s * 1024 + kb + 8]) = xv * wa1 + bb1;
    }
    __syncthreads();

    const int i = i0 + wv;
    const int dij = i - j0;
    const int rgmin = (dij > 0) ? (dij >> 4) : 0;   // wave-uniform skip

    f16 xjs[8];
    #pragma unroll
    for (int rg = 0; rg < 8; rg++) xjs[rg] = xs[j0 + rg * 16 + cL];

    f32x4 acc[8][4];
    #pragma unroll
    for (int rg = 0; rg < 8; rg++)
      #pragma unroll
      for (int cg = 0; cg < 4; cg++) acc[rg][cg] = (f32x4){0.f, 0.f, 0.f, 0.f};

    const f16* hrow  = hat + wv * 1024 + q * 8;
    const f16* wrow  = w1bf + q * 8;
    const f16* bbase = w2f + lane * 8;

    for (int kk = 0; kk < 32; ++kk) {
      const f16x8 hv = *(const f16x8*)(hrow + kk * 32);
      const f16x8 wb = *(const f16x8*)(wrow + kk * 32);
      f16x8 bf[4];
      #pragma unroll
      for (int cg = 0; cg < 4; cg++)
        bf[cg] = *(const f16x8*)(bbase + (cg * 32 + kk) * 512);
      #pragma unroll
      for (int rg = 0; rg < 8; rg++) {
        if (rg >= rgmin) {
          const f16x8 af = relu8(bcast8(xjs[rg]) * wb + hv);
          #pragma unroll
          for (int cg = 0; cg < 4; cg++)
            acc[rg][cg] = __builtin_amdgcn_mfma_f32_16x16x32_f16(af, bf[cg], acc[rg][cg], 0, 0, 0);
        }
      }
    }

    // --- epilogue: dot over this nh's 64 n; direct global writes (1 i/wave)
    float b2v[4], w3v[4];
    #pragma unroll
    for (int cg = 0; cg < 4; cg++) {
      b2v[cg] = b2[nh * 64 + cg * 16 + cL];
      w3v[cg] = W3[nh * 64 + cg * 16 + cL];
    }
    const float badd = (nh == 0) ? b3[0] : 0.f;   // b3 added exactly once
    #pragma unroll
    for (int rg = 0; rg < 8; rg++) {
      if (rg >= rgmin) {
        #pragma unroll
        for (int r = 0; r < 4; r++) {
          float ssum = 0.f;
          #pragma unroll
          for (int cg = 0; cg < 4; cg++)
            ssum = fmaf(fmaxf(acc[rg][cg][r] + b2v[cg], 0.f), w3v[cg], ssum);
          ssum += __shfl_xor(ssum, 1, 64);
          ssum += __shfl_xor(ssum, 2, 64);
          ssum += __shfl_xor(ssum, 4, 64);
          ssum += __shfl_xor(ssum, 8, 64);
          if (cL == 0) {
            const int j = j0 + rg * 16 + q * 4 + r;  // C row = q*4 + reg
            if (j >= i) Kp[i * 512 + j] = ssum + badd;
          }
        }
      }
    }
  }
}

// ---------------------------------------------------------------------------
// atta2 (R17): split-K parallel KtK. One block per (pair a<=b, i-chunk of 32)
// = 816 blocks (~3.2/CU vs old 0.53/CU). float4 loads of Kp0+Kp1; 32x32
// partial tile accumulated into pre-zeroed C via native f32 atomics; mirror
// guarded (pb != qb) to avoid diagonal double-count.
// ---------------------------------------------------------------------------
__global__ __launch_bounds__(256) void k_atta2(const float* __restrict__ K0,
                                               const float* __restrict__ K1,
                                               float* __restrict__ C) {
  __shared__ float sp[32 * 36], sq[32 * 36];
  // decode blockIdx -> (a, b, ic): pair (a,b), a<=b, has a+1 i-chunks
  int a = 0, rem = (int)blockIdx.x;
  #pragma unroll
  for (int aa = 0; aa < 16; aa++) {
    const int c = (16 - aa) * (aa + 1);
    if (rem < c) { a = aa; break; }
    rem -= c;
  }
  const int b = a + rem / (a + 1);
  const int ic = rem % (a + 1);
  const int pb = a * 32, qb = b * 32, i0 = ic * 32;

  const int tid = threadIdx.x;
  const int ii = tid >> 3, p4 = (tid & 7) << 2;   // tile row, col-group of 4
  const int irow = i0 + ii;
  {
    const int gp = irow * 512 + pb + p4, gq = irow * 512 + qb + p4;
    const float4 a0 = *(const float4*)(K0 + gp);
    const float4 a1 = *(const float4*)(K1 + gp);
    const float4 b0 = *(const float4*)(K0 + gq);
    const float4 b1 = *(const float4*)(K1 + gq);
    float vp[4] = {a0.x + a1.x, a0.y + a1.y, a0.z + a1.z, a0.w + a1.w};
    float vq[4] = {b0.x + b1.x, b0.y + b1.y, b0.z + b1.z, b0.w + b1.w};
    #pragma unroll
    for (int e = 0; e < 4; e++) {
      sp[ii * 36 + p4 + e] = (irow <= pb + p4 + e) ? vp[e] : 0.f;  // triu mask
      sq[ii * 36 + p4 + e] = (irow <= qb + p4 + e) ? vq[e] : 0.f;
    }
  }
  __syncthreads();

  const int tx = tid & 15, ty = tid >> 4;
  float c00 = 0.f, c01 = 0.f, c10 = 0.f, c11 = 0.f;
  #pragma unroll 8
  for (int k = 0; k < 32; k++) {
    const float a0 = sp[k * 36 + ty * 2], a1 = sp[k * 36 + ty * 2 + 1];
    const float b0 = sq[k * 36 + tx * 2], b1 = sq[k * 36 + tx * 2 + 1];
    c00 = fmaf(a0, b0, c00); c01 = fmaf(a0, b1, c01);
    c10 = fmaf(a1, b0, c10); c11 = fmaf(a1, b1, c11);
  }
  const int p0 = pb + ty * 2, q0 = qb + tx * 2;
  atomAddF(&C[p0 * 512 + q0], c00);       atomAddF(&C[p0 * 512 + q0 + 1], c01);
  atomAddF(&C[(p0 + 1) * 512 + q0], c10); atomAddF(&C[(p0 + 1) * 512 + q0 + 1], c11);
  if (pb != qb) {   // mirror (never for diagonal pairs: would double-count)
    atomAddF(&C[q0 * 512 + p0], c00);       atomAddF(&C[(q0 + 1) * 512 + p0], c01);
    atomAddF(&C[q0 * 512 + p0 + 1], c10);   atomAddF(&C[(q0 + 1) * 512 + p0 + 1], c11);
  }
}

extern "C" void kernel_launch(void* const* d_in, const int* in_sizes, int n_in,
                              void* d_out, int out_size, void* d_ws, size_t ws_size,
                              hipStream_t stream) {
  const float* x  = (const float*)d_in[0];
  const float* W1 = (const float*)d_in[1];
  const float* b1 = (const float*)d_in[2];
  const float* W2 = (const float*)d_in[3];
  const float* b2 = (const float*)d_in[4];
  const float* W3 = (const float*)d_in[5];
  const float* b3 = (const float*)d_in[6];
  float* out = (float*)d_out;
  char* ws = (char*)d_ws;

  f16* Wtp = (f16*)ws;                              // 256 KB packed W2 B-fragments
  float* Kp0 = (float*)(ws + (256 << 10));          // 1 MB partial K (n 0..63)
  float* Kp1 = (float*)(ws + (256 << 10) + (1 << 20));  // 1 MB partial K (n 64..127)

  (void)hipMemsetAsync(out, 0, 512 * 512 * sizeof(float), stream);
  k_prep<<<64, 256, 0, stream>>>(W2, Wtp);
  k_fused<<<256, 512, 0, stream>>>(x, W1, b1, b2, W3, b3, Wtp, Kp0, Kp1);
  k_atta2<<<816, 256, 0, stream>>>(Kp0, Kp1, out);
}